// Round 12
// baseline (245.256 us; speedup 1.0000x reference)
//
#include <hip/hip_runtime.h>

#define N_NODES 50000
#define N_EDGES 800000
#define R_REL   8

// two-level binning: coarse bucket (256 dst-nodes) -> tile (16 dst-nodes)
#define NCB     196                      // coarse buckets: dst>>8
#define CCAP    5120                     // records per coarse bucket (mean 4082, +16 sigma)
#define TNBKT   3125                     // tiles: 50000/16
#define TCAP    512                      // records per tile (gbin row capacity)
#define SCAP    448                      // in-LDS sorted capacity (256 + 12 sigma)
#define SLAB    4096                     // edges per bin-block
#define BINBLK  ((N_EDGES + SLAB - 1) / SLAB)  // 196

typedef float  f32x4  __attribute__((ext_vector_type(4)));
typedef __bf16 bf16x8 __attribute__((ext_vector_type(8)));

__device__ __forceinline__ unsigned short f2bf(float f) {
    unsigned int u = __float_as_uint(f);
    u = (u + 0x7FFFu + ((u >> 16) & 1u)) >> 16;   // RNE
    return (unsigned short)u;
}
__device__ __forceinline__ float bflo(unsigned int u) { return __uint_as_float(u << 16); }
__device__ __forceinline__ float bfhi(unsigned int u) { return __uint_as_float(u & 0xFFFF0000u); }

__device__ __forceinline__ void acc16(float* a, uint4 u0, uint4 u1) {
    a[0]  += bflo(u0.x);   a[1]  += bfhi(u0.x);
    a[2]  += bflo(u0.y);   a[3]  += bfhi(u0.y);
    a[4]  += bflo(u0.z);   a[5]  += bfhi(u0.z);
    a[6]  += bflo(u0.w);   a[7]  += bfhi(u0.w);
    a[8]  += bflo(u1.x);   a[9]  += bfhi(u1.x);
    a[10] += bflo(u1.y);   a[11] += bfhi(u1.y);
    a[12] += bflo(u1.z);   a[13] += bfhi(u1.z);
    a[14] += bflo(u1.w);   a[15] += bfhi(u1.w);
}

// ---------------- merged prep: COARSE binning + converts in ONE dispatch (R11 proven) ----------------

#define W1_ELEMS (9 * 128 * 128)   // NBt=8
#define W2_ELEMS (9 * 64 * 128)    // NBt=4
#define N4       (N_NODES * 32)    // 1.6M float4 groups
#define NB_CVT   ((N4 + 255) / 256)            // 6250
#define NB_PREP  (BINBLK + NB_CVT)             // 6446

__global__ __launch_bounds__(256) void k_prep(
    const int* __restrict__ src, const int* __restrict__ dst,
    const int* __restrict__ et, int* __restrict__ gcur1,
    unsigned* __restrict__ cbin,
    const float* __restrict__ x, unsigned short* __restrict__ xb,
    const float* __restrict__ root1, const float* __restrict__ W1,
    const float* __restrict__ root2, const float* __restrict__ W2,
    unsigned short* __restrict__ Wt1, unsigned short* __restrict__ Wt2)
{
    __shared__ int hist[256];
    __shared__ int base[256];
    const int t = threadIdx.x;

    if (blockIdx.x < BINBLK) {
        // ---------- coarse-bin branch ----------
        const int e0 = blockIdx.x * SLAB;
        hist[t] = 0;
        __syncthreads();
#pragma unroll
        for (int i = 0; i < SLAB / 256; ++i) {
            int e = e0 + i * 256 + t;
            if (e < N_EDGES) atomicAdd(&hist[dst[e] >> 8], 1);
        }
        __syncthreads();
        {
            int h = hist[t];
            base[t] = (h > 0) ? atomicAdd(&gcur1[t], h) : 0;
            hist[t] = 0;   // reuse as sub-cursor
        }
        __syncthreads();
#pragma unroll
        for (int i = 0; i < SLAB / 256; ++i) {
            int e = e0 + i * 256 + t;
            if (e < N_EDGES) {
                int d = dst[e];
                int b = d >> 8;
                int sub = atomicAdd(&hist[b], 1);
                int pos = base[b] + sub;
                // rec: src(16b) | ltile(4b) | localkey(7b)
                unsigned rec = ((unsigned)src[e] << 11) |
                               ((unsigned)((d >> 4) & 15) << 7) |
                               (unsigned)((d & 15) * 8 + et[e]);
                if (pos < CCAP) cbin[(size_t)b * CCAP + pos] = rec;
            }
        }
        return;
    }

    // ---------- convert branch ----------
    const int idx = (blockIdx.x - BINBLK) * 256 + t;
    if (idx < N4) {
        float4 v = *(const float4*)(x + (size_t)idx * 4);
        ushort4 o;
        o.x = f2bf(v.x); o.y = f2bf(v.y); o.z = f2bf(v.z); o.w = f2bf(v.w);
        *(ushort4*)(xb + (size_t)idx * 4) = o;
    }
    if (idx < W1_ELEMS) {
        int j    = idx & 7;
        int lane = (idx >> 3) & 63;
        int r    = idx >> 9;
        int nb   = r & 7;        // NBt = 8
        int r2   = r >> 3;
        int kk   = r2 & 3;
        int seg  = r2 >> 2;
        int k = kk * 32 + (lane >> 4) * 8 + j;
        int n = nb * 16 + (lane & 15);
        float v = (seg == 0) ? root1[k * 128 + n] : W1[((seg - 1) * 128 + k) * 128 + n];
        Wt1[idx] = f2bf(v);
    } else if (idx < W1_ELEMS + W2_ELEMS) {
        int i2   = idx - W1_ELEMS;
        int j    = i2 & 7;
        int lane = (i2 >> 3) & 63;
        int r    = i2 >> 9;
        int nb   = r & 3;        // NBt = 4
        int r2   = r >> 2;
        int kk   = r2 & 3;
        int seg  = r2 >> 2;
        int k = kk * 32 + (lane >> 4) * 8 + j;
        int n = nb * 16 + (lane & 15);
        float v = (seg == 0) ? root2[k * 64 + n] : W2[((seg - 1) * 128 + k) * 64 + n];
        Wt2[i2] = f2bf(v);
    }
}

// ---------------- part2: refine coarse buckets into per-tile gbin (R11 proven) ----------------

__global__ __launch_bounds__(256) void k_part2(
    const int* __restrict__ gcur1, const unsigned* __restrict__ cbin,
    unsigned* __restrict__ gbin, int* __restrict__ gcnt)
{
    __shared__ int cur[16];
    const int t = threadIdx.x;
    const int b = blockIdx.x;
    if (t < 16) cur[t] = 0;
    __syncthreads();
    const int nraw = gcur1[b];
    const int n = nraw < CCAP ? nraw : CCAP;
    const unsigned* rp = cbin + (size_t)b * CCAP;
    for (int j = t; j < n; j += 256) {
        unsigned rec = rp[j];
        int lt = (rec >> 7) & 15;
        int sub = atomicAdd(&cur[lt], 1);
        if (sub < TCAP) {
            unsigned outrec = ((rec >> 11) << 7) | (rec & 127);   // src<<7 | localkey
            gbin[(size_t)(b * 16 + lt) * TCAP + sub] = outrec;
        }
    }
    __syncthreads();
    if (t < 16) {
        int c = cur[t];
        gcnt[b * 16 + t] = c < TCAP ? c : TCAP;
    }
}

// ---------------- fused: in-LDS CSR build + gather + MFMA ----------------
// R12 change: LDS diet 41,984 -> 40,832 B (<= 163,840/4) to raise co-residency
// 3 -> 4 blocks/CU (+33% resident waves issuing gather loads). Per-LANE ILP
// experiments all failed (R1/R5/R6/R9); per-CU WAVE count was never varied.
// Diet: As0 unpadded [16][128] (its conflicts are off-critical-path -- R2
// proved killing 1.6M conflict-cycles moved nothing), sorted 512->448
// (256+12sigma), dcnt/kbeg u16, histogram runs in int kcur[] then kcur is
// zeroed and reused as scatter cursors. Gather loop, As swizzle, MFMA and
// epilogue byte-identical to the proven 78.5 us kernel.

template <int FOUT, bool RELU, bool OUT_BF16>
__global__ __launch_bounds__(512) void k_fused(
    const unsigned short* __restrict__ xin,  // [N,128] bf16
    const unsigned short* __restrict__ WtP,  // fragment-ordered weights
    const float* __restrict__ bias,          // [FOUT]
    const int* __restrict__ gcnt,            // [TNBKT] tile counts
    const unsigned* __restrict__ gbin,       // [TNBKT][TCAP] records
    unsigned short* __restrict__ outb,       // [N,FOUT] bf16 (if OUT_BF16)
    float* __restrict__ outf)                // [N,FOUT] fp32 (else)
{
    constexpr int NBt = FOUT / 16;           // 8 (L1) / 4 (L2)
    __shared__ __align__(16) unsigned short As0[16][128];      // 4,096 B (root, unpadded)
    __shared__ __align__(16) unsigned short As[8][16][136];    // 34,816 B
    __shared__ unsigned short sorted[SCAP];                    // 896 B
    __shared__ int kcur[128];                                  // 512 B (hist, then cursors)
    __shared__ unsigned short dcnt[128];                       // 256 B
    __shared__ unsigned short kbeg[128];                       // 256 B
    // total 40,832 B <= 40,960 -> 4 blocks/CU

    const int t = threadIdx.x;
    const int node0 = blockIdx.x * 16;

    // ---- P0: zero hist, stage seg0, read my bin record ----
    if (t < 128) kcur[t] = 0;
    if (t < 128) {
        const int sr = t >> 3;
        const int sp = t & 7;
        const uint4* s4 = (const uint4*)(xin + (size_t)(node0 + sr) * 128 + sp * 16);
        uint4 r0 = s4[0], r1 = s4[1];
        uint4* d = (uint4*)&As0[sr][sp * 16];
        d[0] = r0; d[1] = r1;
    }
    const int nraw = gcnt[blockIdx.x];
    const int n = nraw < SCAP ? nraw : SCAP;
    unsigned rec = 0;
    if (t < n) rec = gbin[(size_t)blockIdx.x * TCAP + t];
    __syncthreads();   // bar1: zeros visible

    // ---- P1: per-key histogram (into kcur) ----
    if (t < n) atomicAdd(&kcur[rec & 127], 1);
    __syncthreads();   // bar2

    // ---- P2: wave-0 exclusive scan; stash deg/beg as u16; zero kcur for reuse ----
    if (t < 64) {
        int d0 = kcur[2 * t], d1 = kcur[2 * t + 1];
        int s = d0 + d1;
        int inc = s;
#pragma unroll
        for (int off = 1; off < 64; off <<= 1) {
            int y = __shfl_up(inc, off, 64);
            if (t >= off) inc += y;
        }
        int excl = inc - s;
        kbeg[2 * t]     = (unsigned short)excl;
        kbeg[2 * t + 1] = (unsigned short)(excl + d0);
        dcnt[2 * t]     = (unsigned short)d0;
        dcnt[2 * t + 1] = (unsigned short)d1;
        kcur[2 * t] = 0;
        kcur[2 * t + 1] = 0;
    }
    __syncthreads();   // bar3

    // ---- P3: scatter-sort records into per-key src lists ----
    if (t < n) {
        int key = rec & 127;
        int pos = atomicAdd(&kcur[key], 1);
        sorted[(int)kbeg[key] + pos] = (unsigned short)(rec >> 7);
    }
    __syncthreads();   // bar4: sorted/dcnt/kbeg ready

    // ---- P4: gather, one chain per (node, rel), 4 lanes (32-feat quarters) ----
    {
        const int key = t >> 2;        // nl*8 + rel
        const int q   = t & 3;         // 32-feat quarter
        const int rel = key & 7;
        const int nl  = key >> 3;

        const int beg = kbeg[key];
        const int deg = dcnt[key];
        const int end = beg + deg;

        const unsigned short* bx = xin + q * 32;
        float a[32];
#pragma unroll
        for (int i = 0; i < 32; ++i) a[i] = 0.f;

        int j = beg;
        for (; j + 1 < end; j += 2) {
            int s0 = sorted[j];
            int s1 = sorted[j + 1];
            const uint4* p0 = (const uint4*)(bx + (size_t)s0 * 128);
            const uint4* p1 = (const uint4*)(bx + (size_t)s1 * 128);
            uint4 v0 = p0[0], v1 = p0[1], v2 = p0[2], v3 = p0[3];
            uint4 w0 = p1[0], w1 = p1[1], w2 = p1[2], w3 = p1[3];
            acc16(a, v0, v1);
            acc16(a + 16, v2, v3);
            acc16(a, w0, w1);
            acc16(a + 16, w2, w3);
        }
        if (j < end) {
            int s = sorted[j];
            const uint4* p = (const uint4*)(bx + (size_t)s * 128);
            uint4 v0 = p[0], v1 = p[1], v2 = p[2], v3 = p[3];
            acc16(a, v0, v1);
            acc16(a + 16, v2, v3);
        }

        float scl = 1.f / (float)(deg > 1 ? deg : 1);
        unsigned int pk[16];
#pragma unroll
        for (int i = 0; i < 16; ++i)
            pk[i] = (unsigned int)f2bf(a[i * 2] * scl) |
                    ((unsigned int)f2bf(a[i * 2 + 1] * scl) << 16);
        // swizzled stores: row-local granule (q*4+i) ^ rel
        uint4* G = (uint4*)&As[rel][nl][0];
        const int g0 = q * 4;
        G[(g0 + 0) ^ rel] = make_uint4(pk[0],  pk[1],  pk[2],  pk[3]);
        G[(g0 + 1) ^ rel] = make_uint4(pk[4],  pk[5],  pk[6],  pk[7]);
        G[(g0 + 2) ^ rel] = make_uint4(pk[8],  pk[9],  pk[10], pk[11]);
        G[(g0 + 3) ^ rel] = make_uint4(pk[12], pk[13], pk[14], pk[15]);
    }

    __syncthreads();   // bar5: all 9 A slabs ready

    // ---- P5: MFMA, wave w owns col-tile w ----
    const int lane = t & 63;
    const int w = t >> 6;
    if (w >= NBt) return;            // FOUT=64: waves 4-7 done (no barriers after)
    const int quad = lane >> 4;
    const int tc = lane & 15;

    f32x4 acc = (f32x4){0.f, 0.f, 0.f, 0.f};
    const bf16x8* Bp = (const bf16x8*)WtP;

#pragma unroll
    for (int seg = 0; seg < 9; ++seg) {
        const uint4* Ag = (seg == 0) ? (const uint4*)&As0[tc][0]
                                     : (const uint4*)&As[seg - 1][tc][0];
        const int s = (seg == 0) ? 0 : (seg - 1);   // un-swizzle (uniform per instr)
#pragma unroll
        for (int kk = 0; kk < 4; ++kk) {
            bf16x8 af = *(const bf16x8*)(Ag + (((kk << 2) + quad) ^ s));
            bf16x8 bf = Bp[((seg * 4 + kk) * NBt + w) * 64 + lane];
            acc = __builtin_amdgcn_mfma_f32_16x16x32_bf16(af, bf, acc, 0, 0, 0);
        }
    }

    // epilogue: D layout col = lane&15, row = quad*4 + reg
    const int col = w * 16 + tc;
    const float bs = bias[col];
#pragma unroll
    for (int i = 0; i < 4; ++i) {
        int r = node0 + quad * 4 + i;
        float v = acc[i] + bs;
        if (RELU) v = fmaxf(v, 0.f);
        if (OUT_BF16) outb[(size_t)r * FOUT + col] = f2bf(v);
        else          outf[(size_t)r * FOUT + col] = v;
    }
}

// ---------------- launch ----------------

extern "C" void kernel_launch(void* const* d_in, const int* in_sizes, int n_in,
                              void* d_out, int out_size, void* d_ws, size_t ws_size,
                              hipStream_t stream) {
    const float* x     = (const float*)d_in[0];
    const int*   ei    = (const int*)d_in[1];  // [2][E]: row0=src, row1=dst
    const int*   et    = (const int*)d_in[2];  // [E]
    const float* W1    = (const float*)d_in[3];
    const float* root1 = (const float*)d_in[4];
    const float* b1    = (const float*)d_in[5];
    const float* W2    = (const float*)d_in[6];
    const float* root2 = (const float*)d_in[7];
    const float* b2    = (const float*)d_in[8];
    float* out = (float*)d_out;

    int* ws = (int*)d_ws;
    int* gcur1 = ws;                                  // [256]   coarse cursors
    int* gcnt  = ws + 256;                            // [3200]  tile counts
    unsigned* cbin = (unsigned*)(ws + 3456);          // NCB*CCAP u32 = 4.0 MB
    unsigned* gbin = cbin + (size_t)NCB * CCAP;       // TNBKT*TCAP u32 = 6.4 MB
    unsigned short* xb  = (unsigned short*)(gbin + (size_t)TNBKT * TCAP); // 12.8 MB
    unsigned short* hb  = xb + (size_t)N_NODES * 128;                     // 12.8 MB
    unsigned short* Wt1 = hb + (size_t)N_NODES * 128;                     // 288 KB
    unsigned short* Wt2 = Wt1 + W1_ELEMS;                                 // 144 KB
    // total ws usage ~37 MB (ws = 256 MiB)

    const int* esrc = ei;
    const int* edst = ei + N_EDGES;

    // memset + 4 kernels: prep (coarse-bin ∥ convert) -> part2 -> fused x2
    hipMemsetAsync(gcur1, 0, 256 * sizeof(int), stream);
    k_prep<<<NB_PREP, 256, 0, stream>>>(esrc, edst, et, gcur1, cbin,
                                        x, xb, root1, W1, root2, W2, Wt1, Wt2);
    k_part2<<<NCB, 256, 0, stream>>>(gcur1, cbin, gbin, gcnt);

    const int NT = N_NODES / 16;  // 3125 exactly

    k_fused<128, true,  true ><<<NT, 512, 0, stream>>>(xb, Wt1, b1, gcnt, gbin, hb, nullptr);
    k_fused<64,  false, false><<<NT, 512, 0, stream>>>(hb, Wt2, b2, gcnt, gbin, nullptr, out);
}